// Round 1
// 522.016 us; speedup vs baseline: 1.0203x; 1.0203x over previous
//
#include <hip/hip_runtime.h>
#include <cstdint>
#include <cstddef>

#define N_TOKENS 4096
#define HIDDEN   2048
#define INTER    1024
#define NE       8
#define NE_TOT   10
#define SCALE    2.5f

typedef short v8s __attribute__((ext_vector_type(8)));
typedef float v4f __attribute__((ext_vector_type(4)));

static __device__ inline int imin(int a, int b) { return a < b ? a : b; }

__device__ inline unsigned short f2bf(float f) {
  unsigned int u = __float_as_uint(f);
  u += 0x7fffu + ((u >> 16) & 1u);   // round-to-nearest-even
  return (unsigned short)(u >> 16);
}

__device__ inline void gld_lds16(const void* g, void* l) {
  __builtin_amdgcn_global_load_lds(
      (const __attribute__((address_space(1))) unsigned int*)g,
      (__attribute__((address_space(3))) unsigned int*)l, 16, 0, 0);
}

// ---------------- init: zero per-expert counts ----------------
__global__ void init_kernel(int* counts) {
  if (threadIdx.x < NE) counts[threadIdx.x] = 0;
}

// ---------------- f32 -> bf16 weight conversion ----------------
__global__ __launch_bounds__(256) void cvt_kernel(const float* __restrict__ src,
                                                  unsigned short* __restrict__ dst,
                                                  int n8) {
  int i = blockIdx.x * 256 + threadIdx.x;
  if (i >= n8) return;
  size_t b = (size_t)i * 8;
  float4 a0 = *(const float4*)(src + b);
  float4 a1 = *(const float4*)(src + b + 4);
  union { unsigned short u[8]; uint4 v; } r;
  r.u[0] = f2bf(a0.x); r.u[1] = f2bf(a0.y); r.u[2] = f2bf(a0.z); r.u[3] = f2bf(a0.w);
  r.u[4] = f2bf(a1.x); r.u[5] = f2bf(a1.y); r.u[6] = f2bf(a1.z); r.u[7] = f2bf(a1.w);
  *(uint4*)(dst + b) = r.v;
}

// ---------------- router: no-LDS, 1 token per wave, fused x->bf16 and out = wz*x ----
// rw (80 KB) is read straight from global; it is L2-resident (4 MB/XCD), so the
// 80 KB LDS stage (which capped occupancy at 2 blocks/CU) is pure loss.
__global__ __launch_bounds__(256, 4) void router_kernel(
    const float* __restrict__ x, const float* __restrict__ rw,
    const float* __restrict__ bias, unsigned short* __restrict__ xb,
    int* __restrict__ counts, int* __restrict__ tok_list,
    float* __restrict__ tok_w, float* __restrict__ out) {
  int tid  = threadIdx.x;
  int lane = tid & 63;
  int wid  = tid >> 6;
  int n    = blockIdx.x * 4 + wid;

  const float* xr = x + (size_t)n * HIDDEN;
  float4 xv[8];
#pragma unroll
  for (int i = 0; i < 8; i++) xv[i] = *(const float4*)(xr + (i * 64 + lane) * 4);

  float acc[NE_TOT];
#pragma unroll
  for (int e = 0; e < NE_TOT; e++) {
    const float* wr = rw + (size_t)e * HIDDEN;
    float a = 0.f;
#pragma unroll
    for (int i = 0; i < 8; i++) {
      float4 w = *(const float4*)(wr + (i * 64 + lane) * 4);
      a += xv[i].x * w.x + xv[i].y * w.y + xv[i].z * w.z + xv[i].w * w.w;
    }
    acc[e] = a;
  }
#pragma unroll
  for (int e = 0; e < NE_TOT; e++) {
    float v = acc[e];
#pragma unroll
    for (int off = 32; off > 0; off >>= 1) v += __shfl_xor(v, off, 64);
    acc[e] = v;  // all lanes hold the full dot product
  }

  // sigmoid + bias, top-2 (ties -> lower index), redundantly on all lanes
  float sc[NE_TOT], sb[NE_TOT];
#pragma unroll
  for (int e = 0; e < NE_TOT; e++) {
    sc[e] = 1.f / (1.f + expf(-acc[e]));
    sb[e] = sc[e] + bias[e];
  }
  int i1 = 0;
  for (int e = 1; e < NE_TOT; e++) if (sb[e] > sb[i1]) i1 = e;
  int i2 = (i1 == 0) ? 1 : 0;
  for (int e = 0; e < NE_TOT; e++) if (e != i1 && sb[e] > sb[i2]) i2 = e;
  float wzero = 0.f;
  if (i1 >= NE) wzero += sc[i1];
  if (i2 >= NE) wzero += sc[i2];
  if (lane == 0) {
#pragma unroll
    for (int tt = 0; tt < 2; tt++) {
      int idx = tt == 0 ? i1 : i2;
      if (idx < NE) {
        int slot = atomicAdd(&counts[idx], 1);
        tok_list[idx * N_TOKENS + slot] = n;
        tok_w[idx * N_TOKENS + slot]    = SCALE * sc[idx];
      }
    }
  }
  float wz = SCALE * wzero;
  // fused stores: xb (bf16) and out = wz*x
#pragma unroll
  for (int i = 0; i < 8; i++) {
    int k = (i * 64 + lane) * 4;
    ushort4 ob;
    ob.x = f2bf(xv[i].x); ob.y = f2bf(xv[i].y);
    ob.z = f2bf(xv[i].z); ob.w = f2bf(xv[i].w);
    *(ushort4*)(xb + (size_t)n * HIDDEN + k) = ob;
    float4 o;
    o.x = wz * xv[i].x; o.y = wz * xv[i].y; o.z = wz * xv[i].z; o.w = wz * xv[i].w;
    *(float4*)(out + (size_t)n * HIDDEN + k) = o;
  }
}

// ---------------- prefix offsets over counts ----------------
__global__ void offsets_kernel(const int* __restrict__ counts, int* __restrict__ offsets) {
  if (threadIdx.x == 0) {
    int s = 0;
    for (int e = 0; e < NE; e++) { offsets[e] = s; s += counts[e]; }
  }
}

// LDS xor-swizzle (kills 8-way ds_read_b128 bank conflicts):
// physical 16B chunk p of row r holds logical chunk p ^ ((r>>1)&3).
// Staging (lane tid -> row tid>>2, slot tid&3): fetch global chunk
// (tid&3) ^ ((tid>>3)&3). Readers: physical chunk (lane>>4) ^ ((lane>>1)&3).

// ---------------- gate_up grouped GEMM + fused SiLU*up ----------------
__global__ __launch_bounds__(256, 2) void gateup_kernel(
    const unsigned short* __restrict__ xb, const unsigned short* __restrict__ wgu,
    const int* __restrict__ counts, const int* __restrict__ offsets,
    const int* __restrict__ tok_list, unsigned short* __restrict__ h_buf) {
  int jt = blockIdx.x;  // 16: f-block of 64
  int mt = blockIdx.y;  // 32: token tile of 128
  int e  = blockIdx.z;  // 8
  int count = counts[e];
  if (mt * 128 >= count) return;

  __shared__ unsigned short As[128 * 32];
  __shared__ unsigned short Bs[128 * 32];

  int tid  = threadIdx.x;
  int lane = tid & 63;
  int wm = (tid >> 7) & 1;
  int wn = (tid >> 6) & 1;

  int row0 = tid >> 2, row1 = row0 + 64;
  int col8 = (((tid & 3) ^ ((tid >> 3) & 3)) * 8);  // swizzled source chunk

  const int* tl = tok_list + e * N_TOKENS;
  int t0 = tl[imin(mt * 128 + row0, count - 1)];
  int t1 = tl[imin(mt * 128 + row1, count - 1)];
  const unsigned short* ag0 = xb + (size_t)t0 * HIDDEN + col8;
  const unsigned short* ag1 = xb + (size_t)t1 * HIDDEN + col8;

  int wn0 = row0 >> 6, wi0 = row0 & 63;
  int wn1 = row1 >> 6, wi1 = row1 & 63;
  int br0 = (wi0 < 32) ? (jt * 64 + wn0 * 32 + wi0) : (1024 + jt * 64 + wn0 * 32 + (wi0 - 32));
  int br1 = (wi1 < 32) ? (jt * 64 + wn1 * 32 + wi1) : (1024 + jt * 64 + wn1 * 32 + (wi1 - 32));
  const unsigned short* bbase = wgu + (size_t)e * (2 * INTER) * HIDDEN;
  const unsigned short* bg0 = bbase + (size_t)br0 * HIDDEN + col8;
  const unsigned short* bg1 = bbase + (size_t)br1 * HIDDEN + col8;

  v4f acc[4][4];
#pragma unroll
  for (int i = 0; i < 4; i++)
#pragma unroll
    for (int j = 0; j < 4; j++) acc[i][j] = v4f{0.f, 0.f, 0.f, 0.f};

  int mrow = wm * 64 + (lane & 15);
  int nrow = wn * 64 + (lane & 15);
  int kcol = (((lane >> 4) ^ ((lane >> 1) & 3)) * 8);  // swizzled read chunk

  for (int kt = 0; kt < HIDDEN / 32; kt++) {
    __syncthreads();
    gld_lds16(ag0, &As[(size_t)tid * 8]);
    gld_lds16(ag1, &As[2048 + (size_t)tid * 8]);
    gld_lds16(bg0, &Bs[(size_t)tid * 8]);
    gld_lds16(bg1, &Bs[2048 + (size_t)tid * 8]);
    ag0 += 32; ag1 += 32; bg0 += 32; bg1 += 32;
    __syncthreads();
    v8s a[4], b[4];
#pragma unroll
    for (int i = 0; i < 4; i++) a[i] = *(const v8s*)&As[(mrow + i * 16) * 32 + kcol];
#pragma unroll
    for (int j = 0; j < 4; j++) b[j] = *(const v8s*)&Bs[(nrow + j * 16) * 32 + kcol];
#pragma unroll
    for (int i = 0; i < 4; i++)
#pragma unroll
      for (int j = 0; j < 4; j++)
        acc[i][j] = __builtin_amdgcn_mfma_f32_16x16x32_bf16(a[i], b[j], acc[i][j], 0, 0, 0);
  }

  int ocol  = lane & 15;
  int orow4 = (lane >> 4) * 4;
  int hoff  = offsets[e];
#pragma unroll
  for (int i = 0; i < 4; i++) {
#pragma unroll
    for (int r = 0; r < 4; r++) {
      int m = mt * 128 + wm * 64 + i * 16 + orow4 + r;
      if (m < count) {
        unsigned short* hrow = h_buf + (size_t)(hoff + m) * INTER;
#pragma unroll
        for (int j = 0; j < 2; j++) {
          float g = acc[i][j][r];
          float u = acc[i][j + 2][r];
          float hv = (g / (1.f + expf(-g))) * u;
          hrow[jt * 64 + wn * 32 + j * 16 + ocol] = f2bf(hv);
        }
      }
    }
  }
}

// ---------------- down grouped GEMM, scatter-add into out ----------------
__global__ __launch_bounds__(256, 2) void down_kernel(
    const unsigned short* __restrict__ h_buf, const unsigned short* __restrict__ wd,
    const int* __restrict__ counts, const int* __restrict__ offsets,
    const int* __restrict__ tok_list, const float* __restrict__ tok_w,
    float* __restrict__ out) {
  int nt = blockIdx.x;  // 16: out-col tile of 128
  int mt = blockIdx.y;  // 32
  int e  = blockIdx.z;  // 8
  int count = counts[e];
  if (mt * 128 >= count) return;

  __shared__ unsigned short As[128 * 32];
  __shared__ unsigned short Bs[128 * 32];

  int tid  = threadIdx.x;
  int lane = tid & 63;
  int wm = (tid >> 7) & 1;
  int wn = (tid >> 6) & 1;

  int row0 = tid >> 2, row1 = row0 + 64;
  int col8 = (((tid & 3) ^ ((tid >> 3) & 3)) * 8);
  int hoff = offsets[e];

  const unsigned short* ag0 =
      h_buf + (size_t)(hoff + imin(mt * 128 + row0, count - 1)) * INTER + col8;
  const unsigned short* ag1 =
      h_buf + (size_t)(hoff + imin(mt * 128 + row1, count - 1)) * INTER + col8;
  const unsigned short* bbase = wd + (size_t)e * HIDDEN * INTER;
  const unsigned short* bg0 = bbase + (size_t)(nt * 128 + row0) * INTER + col8;
  const unsigned short* bg1 = bbase + (size_t)(nt * 128 + row1) * INTER + col8;

  v4f acc[4][4];
#pragma unroll
  for (int i = 0; i < 4; i++)
#pragma unroll
    for (int j = 0; j < 4; j++) acc[i][j] = v4f{0.f, 0.f, 0.f, 0.f};

  int mrow = wm * 64 + (lane & 15);
  int nrow = wn * 64 + (lane & 15);
  int kcol = (((lane >> 4) ^ ((lane >> 1) & 3)) * 8);

  for (int kt = 0; kt < INTER / 32; kt++) {
    __syncthreads();
    gld_lds16(ag0, &As[(size_t)tid * 8]);
    gld_lds16(ag1, &As[2048 + (size_t)tid * 8]);
    gld_lds16(bg0, &Bs[(size_t)tid * 8]);
    gld_lds16(bg1, &Bs[2048 + (size_t)tid * 8]);
    ag0 += 32; ag1 += 32; bg0 += 32; bg1 += 32;
    __syncthreads();
    v8s a[4], b[4];
#pragma unroll
    for (int i = 0; i < 4; i++) a[i] = *(const v8s*)&As[(mrow + i * 16) * 32 + kcol];
#pragma unroll
    for (int j = 0; j < 4; j++) b[j] = *(const v8s*)&Bs[(nrow + j * 16) * 32 + kcol];
#pragma unroll
    for (int i = 0; i < 4; i++)
#pragma unroll
      for (int j = 0; j < 4; j++)
        acc[i][j] = __builtin_amdgcn_mfma_f32_16x16x32_bf16(a[i], b[j], acc[i][j], 0, 0, 0);
  }

  int ocol  = lane & 15;
  int orow4 = (lane >> 4) * 4;
#pragma unroll
  for (int i = 0; i < 4; i++) {
#pragma unroll
    for (int r = 0; r < 4; r++) {
      int m = mt * 128 + wm * 64 + i * 16 + orow4 + r;
      if (m < count) {
        int tok  = tok_list[e * N_TOKENS + m];
        float w  = tok_w[e * N_TOKENS + m];
        float* orow = out + (size_t)tok * HIDDEN + nt * 128 + wn * 64 + ocol;
#pragma unroll
        for (int j = 0; j < 4; j++) atomicAdd(orow + j * 16, acc[i][j][r] * w);
      }
    }
  }
}

extern "C" void kernel_launch(void* const* d_in, const int* in_sizes, int n_in,
                              void* d_out, int out_size, void* d_ws, size_t ws_size,
                              hipStream_t stream) {
  const float* x   = (const float*)d_in[0];
  const float* rw  = (const float*)d_in[1];
  const float* cb  = (const float*)d_in[2];
  const float* wgu = (const float*)d_in[3];
  const float* wd  = (const float*)d_in[4];
  float* out = (float*)d_out;

  char* ws = (char*)d_ws;
  size_t off = 0;
  auto alloc = [&](size_t bytes) {
    void* p = ws + off;
    off += (bytes + 255) & ~(size_t)255;
    return p;
  };
  unsigned short* xb    = (unsigned short*)alloc((size_t)N_TOKENS * HIDDEN * 2);
  unsigned short* wgu_b = (unsigned short*)alloc((size_t)NE * 2 * INTER * HIDDEN * 2);
  unsigned short* wd_b  = (unsigned short*)alloc((size_t)NE * HIDDEN * INTER * 2);
  unsigned short* h_buf = (unsigned short*)alloc((size_t)2 * N_TOKENS * INTER * 2);
  int*   tok_list = (int*)alloc((size_t)NE * N_TOKENS * 4);
  float* tok_w    = (float*)alloc((size_t)NE * N_TOKENS * 4);
  int*   counts   = (int*)alloc(256);
  int*   offsets  = (int*)alloc(256);
  (void)ws_size; (void)in_sizes; (void)n_in; (void)out_size;

  init_kernel<<<1, 64, 0, stream>>>(counts);
  cvt_kernel<<<(NE * 2 * INTER * HIDDEN / 8 + 255) / 256, 256, 0, stream>>>(
      wgu, wgu_b, NE * 2 * INTER * HIDDEN / 8);
  cvt_kernel<<<(NE * HIDDEN * INTER / 8 + 255) / 256, 256, 0, stream>>>(
      wd, wd_b, NE * HIDDEN * INTER / 8);
  router_kernel<<<N_TOKENS / 4, 256, 0, stream>>>(x, rw, cb, xb, counts, tok_list, tok_w, out);
  offsets_kernel<<<1, 64, 0, stream>>>(counts, offsets);
  gateup_kernel<<<dim3(16, 32, 8), 256, 0, stream>>>(xb, wgu_b, counts, offsets, tok_list, h_buf);
  down_kernel<<<dim3(16, 32, 8), 256, 0, stream>>>(h_buf, wd_b, counts, offsets, tok_list, tok_w, out);
}